// Round 1
// baseline (2173.978 us; speedup 1.0000x reference)
//
#include <hip/hip_runtime.h>
#include <math.h>

// ---------------------------------------------------------------------------
// Batched PDHG (Chambolle-Pock) for the per-sample LP, exploiting the sparse
// closed-form structure of K = [E; G] (625 x 289, ~1.25K nonzeros).
//
// Layout: one wave (64 lanes) per sample. Lane t (0..47) owns time step t:
//   x-state:  xs (s[t]), xin, xout, xpl, xpr, xep
//   y-state:  ye (eq dual), g1..g12 (ineq duals)
// Lane 48 owns s[48] / ye[48] only. Lanes 49..63 compute benign junk.
// Cross-lane coupling: ye[t-1] (wrap: lane0 <- ye[48]) and z_s[t+1]
// (wrap: lane48 <- z_s[0]) via __shfl.
// ---------------------------------------------------------------------------

#define TT 48
#define N_ITERS 300

__global__ __launch_bounds__(64) void pdhg_kernel(
    const float* __restrict__ price,
    const float* __restrict__ loadv,
    const float* __restrict__ pvv,
    const float* __restrict__ s0,
    float* __restrict__ out,
    int B,
    float tau)
{
    const int b = blockIdx.x;
    const int t = threadIdx.x;
    const bool lt = (t < TT);

    const float A  = 0.999f;
    const float Bi = 0.95f;    // B00
    const float Bo = -1.05f;   // B01
    const float sig  = tau;    // sigma == tau
    const float inv1 = 1.0f / (1.0f + tau * 1e-6f);

    float pr_ = 0.f, ld = 0.f, pv_ = 0.f;
    if (lt) {
        pr_ = price[(size_t)b*TT + t];
        ld  = loadv[(size_t)b*TT + t];
        pv_ = pvv  [(size_t)b*TT + t];
    }
    const float qe = (t == TT) ? s0[b] : 0.f;   // b_eq: zeros(T) then s0

    // h blocks: [-SMIN, SMAX, PS_MAX, 0, PS_MAX, 0, -load, load, -pv, pv, -PG_MIN, PG_MAX]
    const float h2 = 13.5f, h3 = 5.f, h5 = 5.f, h11 = 10.f, h12v = 10.f;
    const float h7 = -ld, h8 = ld, h9 = -pv_, h10 = pv_;

    float xs=0.f, xin=0.f, xout=0.f, xpl=0.f, xpr=0.f, xep=0.f;
    float ye=0.f;
    float g1=0.f,g2=0.f,g3=0.f,g4=0.f,g5=0.f,g6=0.f,
          g7=0.f,g8=0.f,g9=0.f,g10=0.f,g11=0.f,g12=0.f;

    const int prevLane = (t == 0)  ? TT : (t - 1);  // ye[j-1], wrap to ye[48] at j=0
    const int nextLane = (t >= TT) ? 0  : (t + 1);  // z_s[i+1], lane48 reads z_s[0]

    for (int it = 0; it < N_ITERS; ++it) {
        // ---- KTy = K^T y (closed form per column group) ----
        const float yprev = __shfl(ye, prevLane);
        const float d1112 = g11 - g12;
        const float kts   = lt ? (yprev + (g2 - g1) - A*ye) : yprev;
        const float ktin  = (g3 - g4) + d1112 - Bi*ye;
        const float ktout = (g5 - g6) - d1112 - Bo*ye;
        const float ktpl  = (g8 - g7) + d1112;
        const float ktpr  = (g10 - g9) - d1112;
        const float ktep  = -((g7 + g8) + (g9 + g10));

        // ---- xn = (x - tau*(c + KTy)) / (1 + tau*DELTA) ----
        const float xns   = (xs   - tau*kts            ) * inv1;  // c_s = 0
        const float xnin  = (xin  - tau*( pr_   + ktin )) * inv1;
        const float xnout = (xout - tau*(-pr_   + ktout)) * inv1;
        const float xnpl  = (xpl  - tau*( pr_   + ktpl )) * inv1;
        const float xnpr  = (xpr  - tau*(-pr_   + ktpr )) * inv1;
        const float xnep  = (xep  - tau*(1.0e4f + ktep )) * inv1;

        // ---- z = 2*xn - x ----
        const float zs   = 2.f*xns   - xs;
        const float zin  = 2.f*xnin  - xin;
        const float zout = 2.f*xnout - xout;
        const float zpl  = 2.f*xnpl  - xpl;
        const float zpr  = 2.f*xnpr  - xpr;
        const float zep  = 2.f*xnep  - xep;

        const float zsn = __shfl(zs, nextLane);

        // ---- y += sig*(K z - q); clamp inequality part ----
        const float kze = lt ? (zsn - A*zs - Bi*zin - Bo*zout) : zsn; // lane48: z_s[0]
        ye = ye + sig*(kze - qe);

        const float m11 = (zpl - zpr) + (zin - zout);
        g1  = fmaxf(g1  + sig*(-zs               ), 0.f);  // h1 = 0
        g2  = fmaxf(g2  + sig*( zs   - h2        ), 0.f);
        g3  = fmaxf(g3  + sig*( zin  - h3        ), 0.f);
        g4  = fmaxf(g4  + sig*(-zin              ), 0.f);  // h4 = 0
        g5  = fmaxf(g5  + sig*( zout - h5        ), 0.f);
        g6  = fmaxf(g6  + sig*(-zout             ), 0.f);  // h6 = 0
        g7  = fmaxf(g7  + sig*((-zpl - zep) - h7 ), 0.f);
        g8  = fmaxf(g8  + sig*(( zpl - zep) - h8 ), 0.f);
        g9  = fmaxf(g9  + sig*((-zpr - zep) - h9 ), 0.f);
        g10 = fmaxf(g10 + sig*(( zpr - zep) - h10), 0.f);
        g11 = fmaxf(g11 + sig*( m11  - h11       ), 0.f);
        g12 = fmaxf(g12 + sig*(-m11  - h12v      ), 0.f);

        xs = xns; xin = xnin; xout = xnout; xpl = xnpl; xpr = xnpr; xep = xnep;
    }

    if (lt) {
        const size_t BT   = (size_t)B * TT;
        const size_t base = (size_t)b * TT + t;
        out[0*BT + base] = xin;   // Ps_in
        out[1*BT + base] = xout;  // Ps_out
        out[2*BT + base] = xpl;   // Pl
        out[3*BT + base] = xpr;   // Pr
        out[4*BT + base] = xep;   // eps
    }
}

// ---------------------------------------------------------------------------
// Host: spectral norm of K via double-precision power iteration on the same
// closed-form operators. Deterministic (fixed LCG init, fixed iteration
// count) -> graph-capture safe; tau passed by value as a kernel argument.
// ---------------------------------------------------------------------------
static float compute_tau_host()
{
    const double A = 0.999, Bi = 0.95, Bo = -1.05;
    double s[TT+1], in_[TT], out_[TT], pl[TT], prr[TT], ep[TT];

    // deterministic pseudo-random init (avoid starting orthogonal to top SV)
    unsigned long long lcg = 0x243F6A8885A308D3ull;
    auto rnd = [&lcg]() -> double {
        lcg = lcg * 6364136223846793005ull + 1442695040888963407ull;
        return ((double)(lcg >> 11) / 9007199254740992.0) - 0.5;
    };
    for (int j = 0; j <= TT; ++j) s[j] = rnd();
    for (int t = 0; t < TT; ++t) { in_[t]=rnd(); out_[t]=rnd(); pl[t]=rnd(); prr[t]=rnd(); ep[t]=rnd(); }

    double lam = 1.0;
    for (int it = 0; it < 12000; ++it) {
        double we[TT+1], wg[12][TT];
        for (int t = 0; t < TT; ++t) {
            we[t]     = s[t+1] - A*s[t] - Bi*in_[t] - Bo*out_[t];
            wg[0][t]  = -s[t];
            wg[1][t]  =  s[t];
            wg[2][t]  =  in_[t];
            wg[3][t]  = -in_[t];
            wg[4][t]  =  out_[t];
            wg[5][t]  = -out_[t];
            wg[6][t]  = -pl[t]  - ep[t];
            wg[7][t]  =  pl[t]  - ep[t];
            wg[8][t]  = -prr[t] - ep[t];
            wg[9][t]  =  prr[t] - ep[t];
            wg[10][t] = -prr[t] + pl[t] + in_[t] - out_[t];
            wg[11][t] = -wg[10][t];
        }
        we[TT] = s[0];

        double ns[TT+1], nin[TT], nout[TT], npl[TT], npr[TT], nep[TT];
        for (int j = 0; j <= TT; ++j) {
            double v = (j >= 1) ? we[j-1] : we[TT];
            if (j < TT) v += -A*we[j] + (wg[1][j] - wg[0][j]);
            ns[j] = v;
        }
        for (int t = 0; t < TT; ++t) {
            nin[t]  = -Bi*we[t] + wg[2][t] - wg[3][t] + wg[10][t] - wg[11][t];
            nout[t] = -Bo*we[t] + wg[4][t] - wg[5][t] - wg[10][t] + wg[11][t];
            npl[t]  = -wg[6][t] + wg[7][t] + wg[10][t] - wg[11][t];
            npr[t]  = -wg[8][t] + wg[9][t] - wg[10][t] + wg[11][t];
            nep[t]  = -(wg[6][t] + wg[7][t] + wg[8][t] + wg[9][t]);
        }

        double n2 = 0.0;
        for (int j = 0; j <= TT; ++j) n2 += ns[j]*ns[j];
        for (int t = 0; t < TT; ++t)
            n2 += nin[t]*nin[t] + nout[t]*nout[t] + npl[t]*npl[t] + npr[t]*npr[t] + nep[t]*nep[t];
        const double nrm = sqrt(n2);
        lam = nrm;  // ||K^T K v|| with ||v||=1  ->  sigma_max^2
        const double inv = 1.0 / nrm;
        for (int j = 0; j <= TT; ++j) s[j] = ns[j]*inv;
        for (int t = 0; t < TT; ++t) {
            in_[t]=nin[t]*inv; out_[t]=nout[t]*inv; pl[t]=npl[t]*inv;
            prr[t]=npr[t]*inv; ep[t]=nep[t]*inv;
        }
    }
    const double knorm = sqrt(lam);
    return (float)(0.95 / knorm);
}

extern "C" void kernel_launch(void* const* d_in, const int* in_sizes, int n_in,
                              void* d_out, int out_size, void* d_ws, size_t ws_size,
                              hipStream_t stream)
{
    const float* price = (const float*)d_in[0];
    const float* loadv = (const float*)d_in[1];
    const float* pvv   = (const float*)d_in[2];
    const float* s0    = (const float*)d_in[3];
    float* out = (float*)d_out;

    const int B = in_sizes[0] / TT;   // price_hat is (B, T)
    const float tau = compute_tau_host();

    pdhg_kernel<<<B, 64, 0, stream>>>(price, loadv, pvv, s0, out, B, tau);
}

// Round 3
// 71.656 us; speedup vs baseline: 30.3389x; 30.3389x over previous
//
#include <hip/hip_runtime.h>
#include <math.h>

// ---------------------------------------------------------------------------
// Batched PDHG (Chambolle-Pock), one wave per sample, lane t owns time step t.
// Cross-lane shift-by-one via DPP row shifts (row_shr:1 / row_shl:1) with
// readlane + cndmask boundary fixups. No LDS anywhere -> no ds_bpermute
// latency on the serial dependence chain.
// ---------------------------------------------------------------------------

#define TT 48
#define N_ITERS 300

// lane l <- v[l-1] (l=1..48), lane 0 <- v[48]. Fixup lanes: 0,16,32,48.
__device__ __forceinline__ float lane_shift_up(float v, bool b0, bool b16, bool b32, bool b48) {
    int iv  = __float_as_int(v);
    int s15 = __builtin_amdgcn_readlane(iv, 15);
    int s31 = __builtin_amdgcn_readlane(iv, 31);
    int s47 = __builtin_amdgcn_readlane(iv, 47);
    int s48 = __builtin_amdgcn_readlane(iv, 48);
    int sh  = __builtin_amdgcn_update_dpp(iv, iv, 0x111, 0xF, 0xF, false); // row_shr:1
    sh = b0  ? s48 : sh;
    sh = b16 ? s15 : sh;
    sh = b32 ? s31 : sh;
    sh = b48 ? s47 : sh;
    return __int_as_float(sh);
}

// lane l <- v[l+1] (l=0..47), lane 48 <- v[0]. Fixup lanes: 15,31,47,48.
__device__ __forceinline__ float lane_shift_dn(float v, bool b15, bool b31, bool b47, bool b48) {
    int iv  = __float_as_int(v);
    int s16 = __builtin_amdgcn_readlane(iv, 16);
    int s32 = __builtin_amdgcn_readlane(iv, 32);
    int s48 = __builtin_amdgcn_readlane(iv, 48);
    int s0  = __builtin_amdgcn_readlane(iv, 0);
    int sh  = __builtin_amdgcn_update_dpp(iv, iv, 0x101, 0xF, 0xF, false); // row_shl:1
    sh = b15 ? s16 : sh;
    sh = b31 ? s32 : sh;
    sh = b47 ? s48 : sh;
    sh = b48 ? s0  : sh;
    return __int_as_float(sh);
}

__global__ __launch_bounds__(64) void pdhg_kernel(
    const float* __restrict__ price,
    const float* __restrict__ loadv,
    const float* __restrict__ pvv,
    const float* __restrict__ s0,
    float* __restrict__ out,
    int B,
    float tau)
{
    const int b = blockIdx.x;
    const int t = threadIdx.x;
    const bool lt = (t < TT);

    const float A  = 0.999f;
    const float Bi = 0.95f;    // B00
    const float Bo = -1.05f;   // B01
    const float sig  = tau;    // sigma == tau
    const float inv1 = 1.0f / (1.0f + tau * 1e-6f);

    // boundary-lane predicates (loop-invariant -> SGPR masks)
    const bool u0  = (t == 0),  u16 = (t == 16), u32 = (t == 32), u48 = (t == 48);
    const bool d15 = (t == 15), d31 = (t == 31), d47 = (t == 47);

    float pr_ = 0.f, ld = 0.f, pv_ = 0.f;
    if (lt) {
        pr_ = price[(size_t)b*TT + t];
        ld  = loadv[(size_t)b*TT + t];
        pv_ = pvv  [(size_t)b*TT + t];
    }
    const float qe = u48 ? s0[b] : 0.f;   // b_eq: zeros(T) then s0

    // loop-invariant precomputes
    const float sqe   = sig * qe;
    const float tpr   = tau * pr_;
    const float tep   = tau * 1.0e4f;
    const float sgh2  = sig * 13.5f;
    const float sgh3  = sig * 5.0f;
    const float sgh5  = sig * 5.0f;
    const float sgh7  = sig * (-ld);
    const float sgh8  = sig * ld;
    const float sgh9  = sig * (-pv_);
    const float sgh10 = sig * pv_;
    const float sgh11 = sig * 10.0f;
    const float sgh12 = sig * 10.0f;

    float xs=0.f, xin=0.f, xout=0.f, xpl=0.f, xpr=0.f, xep=0.f;
    float ye=0.f;
    float g1=0.f,g2=0.f,g3=0.f,g4=0.f,g5=0.f,g6=0.f,
          g7=0.f,g8=0.f,g9=0.f,g10=0.f,g11=0.f,g12=0.f;

    #pragma unroll 2
    for (int it = 0; it < N_ITERS; ++it) {
        // ---- KTy = K^T y (closed form) ----
        const float yprev = lane_shift_up(ye, u0, u16, u32, u48);
        const float d1112 = g11 - g12;
        const float kts   = lt ? (yprev + (g2 - g1) - A*ye) : yprev;
        const float ktin  = (g3 - g4) + d1112 - Bi*ye;
        const float ktout = (g5 - g6) - d1112 - Bo*ye;
        const float ktpl  = (g8 - g7) + d1112;
        const float ktpr  = (g10 - g9) - d1112;
        const float ktep  = -((g7 + g8) + (g9 + g10));

        // ---- xn = (x - tau*(c + KTy)) / (1 + tau*DELTA) ----
        const float xns   = (xs   - tau*kts        ) * inv1;
        const float xnin  = (xin  - tpr - tau*ktin ) * inv1;
        const float xnout = (xout + tpr - tau*ktout) * inv1;
        const float xnpl  = (xpl  - tpr - tau*ktpl ) * inv1;
        const float xnpr  = (xpr  + tpr - tau*ktpr ) * inv1;
        const float xnep  = (xep  - tep - tau*ktep ) * inv1;

        // ---- z = 2*xn - x ----
        const float zs   = 2.f*xns   - xs;
        const float zin  = 2.f*xnin  - xin;
        const float zout = 2.f*xnout - xout;
        const float zpl  = 2.f*xnpl  - xpl;
        const float zpr  = 2.f*xnpr  - xpr;
        const float zep  = 2.f*xnep  - xep;

        const float zsn = lane_shift_dn(zs, d15, d31, d47, u48);

        // ---- y += sig*(K z - q); clamp inequality part ----
        const float kze = lt ? (zsn - A*zs - Bi*zin - Bo*zout) : zsn;
        ye = ye + sig*kze - sqe;

        const float m11  = (zpl - zpr) + (zin - zout);
        const float s78  = zpl + zep;
        const float d78  = zpl - zep;
        const float s910 = zpr + zep;
        const float d910 = zpr - zep;

        g1  = fmaxf(g1  - sig*zs,            0.f);
        g2  = fmaxf(g2  + sig*zs   - sgh2,   0.f);
        g3  = fmaxf(g3  + sig*zin  - sgh3,   0.f);
        g4  = fmaxf(g4  - sig*zin,           0.f);
        g5  = fmaxf(g5  + sig*zout - sgh5,   0.f);
        g6  = fmaxf(g6  - sig*zout,          0.f);
        g7  = fmaxf(g7  - sig*s78  - sgh7,   0.f);
        g8  = fmaxf(g8  + sig*d78  - sgh8,   0.f);
        g9  = fmaxf(g9  - sig*s910 - sgh9,   0.f);
        g10 = fmaxf(g10 + sig*d910 - sgh10,  0.f);
        g11 = fmaxf(g11 + sig*m11  - sgh11,  0.f);
        g12 = fmaxf(g12 - sig*m11  - sgh12,  0.f);

        xs = xns; xin = xnin; xout = xnout; xpl = xnpl; xpr = xnpr; xep = xnep;
    }

    if (lt) {
        const size_t BT   = (size_t)B * TT;
        const size_t base = (size_t)b * TT + t;
        out[0*BT + base] = xin;   // Ps_in
        out[1*BT + base] = xout;  // Ps_out
        out[2*BT + base] = xpl;   // Pl
        out[3*BT + base] = xpr;   // Pr
        out[4*BT + base] = xep;   // eps
    }
}

// ---------------------------------------------------------------------------
// Host: ||K||_2 via matrix-free Lanczos (m=56, no reorth) on M = K^T K
// (289-dim closed form), lambda_max(T_m) via Sturm bisection. Deterministic,
// ~0.2 Mflop (~tens of microseconds). tau passed by value (capture-safe).
//   us[j]  = we[j-1] (j>=1, else we[48]) + [j<=47]( -A*we[j] + 2 vs[j] )
//   uin    = -Bi*we + 2 vin + 2 w11       uout = -Bo*we + 2 vout - 2 w11
//   upl    = 2 vpl + 2 w11                upr  = 2 vpr - 2 w11
//   uep    = 4 vep          (w11 = vin - vout + vpl - vpr,
//                            we[t] = vs[t+1] - A vs[t] - Bi vin[t] - Bo vout[t])
// ---------------------------------------------------------------------------
static float compute_tau_host()
{
    const double A = 0.999, Bi = 0.95, Bo = -1.05;
    const int n = 289;            // 49 + 5*48
    const int OS = 0, OI = 49, OO = 97, OPL = 145, OPR = 193, OE = 241;

    double q[289], qp[289], w[289];

    auto applyM = [&](const double* v, double* u) {
        double we[TT + 1];
        for (int t = 0; t < TT; ++t)
            we[t] = v[OS + t + 1] - A * v[OS + t] - Bi * v[OI + t] - Bo * v[OO + t];
        we[TT] = v[OS + 0];
        for (int j = 0; j <= TT; ++j) {
            double r = (j >= 1) ? we[j - 1] : we[TT];
            if (j <= TT - 1) r += -A * we[j] + 2.0 * v[OS + j];
            u[OS + j] = r;
        }
        for (int t = 0; t < TT; ++t) {
            const double w11 = v[OI + t] - v[OO + t] + v[OPL + t] - v[OPR + t];
            u[OI  + t] = -Bi * we[t] + 2.0 * v[OI  + t] + 2.0 * w11;
            u[OO  + t] = -Bo * we[t] + 2.0 * v[OO  + t] - 2.0 * w11;
            u[OPL + t] =  2.0 * v[OPL + t] + 2.0 * w11;
            u[OPR + t] =  2.0 * v[OPR + t] - 2.0 * w11;
            u[OE  + t] =  4.0 * v[OE  + t];
        }
    };

    // deterministic init, normalized
    unsigned long long lcg = 0x243F6A8885A308D3ull;
    for (int i = 0; i < n; ++i) {
        lcg = lcg * 6364136223846793005ull + 1442695040888963407ull;
        q[i] = ((double)(lcg >> 11) / 9007199254740992.0) - 0.5;
    }
    {
        double s = 0; for (int i = 0; i < n; ++i) s += q[i]*q[i];
        const double inv = 1.0 / sqrt(s);
        for (int i = 0; i < n; ++i) q[i] *= inv;
    }

    // Lanczos, m up to 56, no reorthogonalization (lambda_max is robust)
    const int MMAX = 56;
    double alpha[MMAX], beta[MMAX];
    for (int i = 0; i < n; ++i) qp[i] = 0.0;
    double bprev = 0.0;
    int m = MMAX;
    for (int j = 0; j < MMAX; ++j) {
        applyM(q, w);
        if (j > 0) for (int i = 0; i < n; ++i) w[i] -= bprev * qp[i];
        double a = 0; for (int i = 0; i < n; ++i) a += w[i] * q[i];
        alpha[j] = a;
        for (int i = 0; i < n; ++i) w[i] -= a * q[i];
        double s = 0; for (int i = 0; i < n; ++i) s += w[i]*w[i];
        const double bnx = sqrt(s);
        if (bnx < 1e-12) { m = j + 1; break; }
        beta[j] = bnx;
        const double inv = 1.0 / bnx;
        for (int i = 0; i < n; ++i) { qp[i] = q[i]; q[i] = w[i] * inv; }
        bprev = bnx;
    }

    // lambda_max(T_m) via Sturm-sequence bisection (Gershgorin upper bound)
    double hi = 0.0;
    for (int i = 0; i < m; ++i) {
        double g = alpha[i] + (i > 0 ? fabs(beta[i-1]) : 0.0)
                            + (i < m-1 ? fabs(beta[i]) : 0.0);
        if (g > hi) hi = g;
    }
    hi += 1e-9; double lo = 0.0;
    for (int it = 0; it < 64; ++it) {
        const double mid = 0.5 * (lo + hi);
        int cnt = 0; double d = 1.0;
        for (int i = 0; i < m; ++i) {
            double tt = alpha[i] - mid - (i > 0 ? beta[i-1]*beta[i-1] / d : 0.0);
            if (tt < 0) ++cnt;
            if (fabs(tt) < 1e-30) tt = -1e-30;
            d = tt;
        }
        if (cnt >= m) hi = mid; else lo = mid;
    }
    double lam = 0.5 * (lo + hi);

    // safety: Rayleigh quotient of the last Lanczos vector is a lower bound
    applyM(q, w);
    double rq = 0, nq = 0;
    for (int i = 0; i < n; ++i) { rq += q[i]*w[i]; nq += q[i]*q[i]; }
    rq /= nq;
    if (rq > lam) lam = rq;

    return (float)(0.95 / sqrt(lam));
}

extern "C" void kernel_launch(void* const* d_in, const int* in_sizes, int n_in,
                              void* d_out, int out_size, void* d_ws, size_t ws_size,
                              hipStream_t stream)
{
    const float* price = (const float*)d_in[0];
    const float* loadv = (const float*)d_in[1];
    const float* pvv   = (const float*)d_in[2];
    const float* s0    = (const float*)d_in[3];
    float* out = (float*)d_out;

    const int B = in_sizes[0] / TT;   // price_hat is (B, T)
    const float tau = compute_tau_host();

    pdhg_kernel<<<B, 64, 0, stream>>>(price, loadv, pvv, s0, out, B, tau);
}

// Round 4
// 47.265 us; speedup vs baseline: 45.9958x; 1.5161x over previous
//
#include <hip/hip_runtime.h>
#include <math.h>

// ---------------------------------------------------------------------------
// Batched PDHG (Chambolle-Pock), one wave per sample, lane t owns time step t.
// Round-4 structure:
//  - duals scaled by tau (ghat = tau*g): K^T side needs no tau multiplies
//  - state stored as float2 (ext_vector) pairs -> v_pk_* packed FP32 ops
//  - shifts via __shfl (ds_bpermute), latency overlapped with independent work
//  - inv1 = 1/(1+tau*1e-6) dropped (|error| < 1e-4 over 300 iters)
// ---------------------------------------------------------------------------

#define TT 48
#define N_ITERS 300

typedef float v2 __attribute__((ext_vector_type(2)));

__device__ __forceinline__ v2 vfma(v2 a, v2 b, v2 c) {
    return __builtin_elementwise_fma(a, b, c);
}
__device__ __forceinline__ v2 vmax0(v2 a) {
    return __builtin_elementwise_max(a, (v2)(0.f));
}

__global__ __launch_bounds__(64) void pdhg_kernel(
    const float* __restrict__ price,
    const float* __restrict__ loadv,
    const float* __restrict__ pvv,
    const float* __restrict__ s0,
    float* __restrict__ out,
    int B,
    float tau)
{
    const int b = blockIdx.x;
    const int t = threadIdx.x;
    const bool lt = (t < TT);

    const float A  = 0.999f;
    const float Bi = 0.95f;    // B00
    const float Bo = -1.05f;   // B01
    const float ts = tau * tau;     // tau*sigma (sigma == tau)

    float pr_ = 0.f, ld = 0.f, pv_ = 0.f;
    if (lt) {
        pr_ = price[(size_t)b*TT + t];
        ld  = loadv[(size_t)b*TT + t];
        pv_ = pvv  [(size_t)b*TT + t];
    }
    const float qe   = (t == TT) ? s0[b] : 0.f;   // b_eq: zeros(T) then s0
    const float tsqe = ts * qe;

    // hoisted per-lane constant vectors
    const v2 tsv   = (v2)(ts);
    const v2 ntsv  = (v2)(-ts);
    const v2 BiBov = { -Bi, -Bo };
    const v2 tpv   = { tau * pr_, -tau * pr_ };    // tau*c for (in,out) and (pl,pr)
    const float tep = tau * 1.0e4f;                // tau*c_eps
    const v2 C12   = { 0.f,        ts * 13.5f };
    const v2 C35   = { ts * 5.f,   ts * 5.f   };
    const v2 C79   = { ts * (-ld), ts * (-pv_) };
    const v2 C810  = { ts * ld,    ts * pv_   };
    const v2 C1112 = { ts * 10.f,  ts * 10.f  };

    const int prevLane = (t == 0)  ? TT : (t - 1);  // ye[j-1], wrap to ye[48]
    const int nextLane = (t >= TT) ? 0  : (t + 1);  // z_s[i+1], lane48 <- z_s[0]

    // primal state: xs scalar; pairs (in,out), (pl,pr); ep scalar
    float xs = 0.f, xep = 0.f;
    v2 xIO = (v2)(0.f), xPP = (v2)(0.f);
    // dual state (scaled by tau): ye scalar; rows paired
    float ye = 0.f;
    v2 G12 = (v2)(0.f), G35 = (v2)(0.f), G46 = (v2)(0.f),
       G79 = (v2)(0.f), G810 = (v2)(0.f), G1112 = (v2)(0.f);

    #pragma unroll 2
    for (int it = 0; it < N_ITERS; ++it) {
        // issue the up-shift early; everything except the s-path is independent
        const float yprev = __shfl(ye, prevLane);

        // ---- K^T y on scaled duals (= tau * K^T y) ----
        const float d1112 = G1112.x - G1112.y;
        const v2 dv    = { d1112, -d1112 };
        const v2 ktIO  = vfma((v2)(ye), BiBov, (G35 - G46) + dv);
        const v2 ktPP  = (G810 - G79) + dv;
        const v2 S     = G79 + G810;
        const float wep = tep - (S.x + S.y);        // tau*(c_ep + ktep)

        // ---- x' = x - (tau*c + tau*K^T y);  z = 2x' - x = x' - w ----
        const v2 wIO = ktIO + tpv;
        const v2 wPP = ktPP + tpv;
        const v2 xnIO = xIO - wIO;  const v2 zIO = xnIO - wIO;
        const v2 xnPP = xPP - wPP;  const v2 zPP = xnPP - wPP;
        const float xnep = xep - wep;  const float zep = xnep - wep;

        // s-path (consumes yprev)
        float kts = (yprev + (G12.y - G12.x)) - A * ye;
        kts = lt ? kts : yprev;
        const float xns = xs - kts;
        const float zs  = xns - kts;

        const float zsn = __shfl(zs, nextLane);     // issue down-shift early

        // ---- dual rows: G' = max(G + ts*e - ts*h, 0), e = rows of K z ----
        const v2 zsv  = { -zs, zs };
        const v2 zepv = (v2)(zep);
        const v2 sv   = zPP + zepv;                 // (zpl+zep, zpr+zep)
        const v2 dvv  = zPP - zepv;                 // (zpl-zep, zpr-zep)
        const float m11 = (zIO.x - zIO.y) + (zPP.x - zPP.y);
        const v2 m11v = { m11, -m11 };

        G12   = vmax0(vfma(zsv,  tsv,  G12)  - C12);
        G35   = vmax0(vfma(zIO,  tsv,  G35)  - C35);
        G46   = vmax0(vfma(zIO,  ntsv, G46));           // h = 0
        G79   = vmax0(vfma(sv,   ntsv, G79)  - C79);
        G810  = vmax0(vfma(dvv,  tsv,  G810) - C810);
        G1112 = vmax0(vfma(m11v, tsv,  G1112) - C1112);

        // ---- equality dual (consumes zsn) ----
        float kze = fmaf(-A, zs, zsn);
        kze = fmaf(-Bi, zIO.x, kze);
        kze = fmaf(-Bo, zIO.y, kze);
        kze = lt ? kze : zsn;                       // lane 48: z_s[0]
        ye  = fmaf(ts, kze, ye) - tsqe;

        xs = xns; xIO = xnIO; xPP = xnPP; xep = xnep;
    }

    if (lt) {
        const size_t BT   = (size_t)B * TT;
        const size_t base = (size_t)b * TT + t;
        out[0*BT + base] = xIO.x;  // Ps_in
        out[1*BT + base] = xIO.y;  // Ps_out
        out[2*BT + base] = xPP.x;  // Pl
        out[3*BT + base] = xPP.y;  // Pr
        out[4*BT + base] = xep;    // eps
    }
}

// ---------------------------------------------------------------------------
// Host: ||K||_2 via matrix-free Lanczos (m=56, no reorth) on M = K^T K
// (289-dim closed form), lambda_max(T_m) via Sturm bisection. Deterministic.
// ---------------------------------------------------------------------------
static float compute_tau_host()
{
    const double A = 0.999, Bi = 0.95, Bo = -1.05;
    const int n = 289;            // 49 + 5*48
    const int OS = 0, OI = 49, OO = 97, OPL = 145, OPR = 193, OE = 241;

    double q[289], qp[289], w[289];

    auto applyM = [&](const double* v, double* u) {
        double we[TT + 1];
        for (int t = 0; t < TT; ++t)
            we[t] = v[OS + t + 1] - A * v[OS + t] - Bi * v[OI + t] - Bo * v[OO + t];
        we[TT] = v[OS + 0];
        for (int j = 0; j <= TT; ++j) {
            double r = (j >= 1) ? we[j - 1] : we[TT];
            if (j <= TT - 1) r += -A * we[j] + 2.0 * v[OS + j];
            u[OS + j] = r;
        }
        for (int t = 0; t < TT; ++t) {
            const double w11 = v[OI + t] - v[OO + t] + v[OPL + t] - v[OPR + t];
            u[OI  + t] = -Bi * we[t] + 2.0 * v[OI  + t] + 2.0 * w11;
            u[OO  + t] = -Bo * we[t] + 2.0 * v[OO  + t] - 2.0 * w11;
            u[OPL + t] =  2.0 * v[OPL + t] + 2.0 * w11;
            u[OPR + t] =  2.0 * v[OPR + t] - 2.0 * w11;
            u[OE  + t] =  4.0 * v[OE  + t];
        }
    };

    // deterministic init, normalized
    unsigned long long lcg = 0x243F6A8885A308D3ull;
    for (int i = 0; i < n; ++i) {
        lcg = lcg * 6364136223846793005ull + 1442695040888963407ull;
        q[i] = ((double)(lcg >> 11) / 9007199254740992.0) - 0.5;
    }
    {
        double s = 0; for (int i = 0; i < n; ++i) s += q[i]*q[i];
        const double inv = 1.0 / sqrt(s);
        for (int i = 0; i < n; ++i) q[i] *= inv;
    }

    const int MMAX = 56;
    double alpha[MMAX], beta[MMAX];
    for (int i = 0; i < n; ++i) qp[i] = 0.0;
    double bprev = 0.0;
    int m = MMAX;
    for (int j = 0; j < MMAX; ++j) {
        applyM(q, w);
        if (j > 0) for (int i = 0; i < n; ++i) w[i] -= bprev * qp[i];
        double a = 0; for (int i = 0; i < n; ++i) a += w[i] * q[i];
        alpha[j] = a;
        for (int i = 0; i < n; ++i) w[i] -= a * q[i];
        double s = 0; for (int i = 0; i < n; ++i) s += w[i]*w[i];
        const double bnx = sqrt(s);
        if (bnx < 1e-12) { m = j + 1; break; }
        beta[j] = bnx;
        const double inv = 1.0 / bnx;
        for (int i = 0; i < n; ++i) { qp[i] = q[i]; q[i] = w[i] * inv; }
        bprev = bnx;
    }

    double hi = 0.0;
    for (int i = 0; i < m; ++i) {
        double g = alpha[i] + (i > 0 ? fabs(beta[i-1]) : 0.0)
                            + (i < m-1 ? fabs(beta[i]) : 0.0);
        if (g > hi) hi = g;
    }
    hi += 1e-9; double lo = 0.0;
    for (int it = 0; it < 64; ++it) {
        const double mid = 0.5 * (lo + hi);
        int cnt = 0; double d = 1.0;
        for (int i = 0; i < m; ++i) {
            double tt = alpha[i] - mid - (i > 0 ? beta[i-1]*beta[i-1] / d : 0.0);
            if (tt < 0) ++cnt;
            if (fabs(tt) < 1e-30) tt = -1e-30;
            d = tt;
        }
        if (cnt >= m) hi = mid; else lo = mid;
    }
    double lam = 0.5 * (lo + hi);

    applyM(q, w);
    double rq = 0, nq = 0;
    for (int i = 0; i < n; ++i) { rq += q[i]*w[i]; nq += q[i]*q[i]; }
    rq /= nq;
    if (rq > lam) lam = rq;

    return (float)(0.95 / sqrt(lam));
}

extern "C" void kernel_launch(void* const* d_in, const int* in_sizes, int n_in,
                              void* d_out, int out_size, void* d_ws, size_t ws_size,
                              hipStream_t stream)
{
    const float* price = (const float*)d_in[0];
    const float* loadv = (const float*)d_in[1];
    const float* pvv   = (const float*)d_in[2];
    const float* s0    = (const float*)d_in[3];
    float* out = (float*)d_out;

    const int B = in_sizes[0] / TT;   // price_hat is (B, T)
    const float tau = compute_tau_host();

    pdhg_kernel<<<B, 64, 0, stream>>>(price, loadv, pvv, s0, out, B, tau);
}

// Round 5
// 43.950 us; speedup vs baseline: 49.4653x; 1.0754x over previous
//
#include <hip/hip_runtime.h>
#include <math.h>

// ---------------------------------------------------------------------------
// Batched PDHG (Chambolle-Pock), one wave per sample, lane t owns time step t.
// Round-5 structure (delta vs round 4):
//  - cross-lane shift-by-one via WAVE-level DPP (wave_shr:1 / wave_shl:1),
//    which crosses 16-lane row boundaries -> only the wrap lane needs a
//    readlane+cndmask fixup (vs 4 for row DPP, vs ~120cyc LDS for bpermute)
//  - dv / m11 pair construction via .yx swizzles (VOP3P op_sel)
//  - everything else identical to the round-4 kernel (passed, absmax 0.031)
// ---------------------------------------------------------------------------

#define TT 48
#define N_ITERS 300

typedef float v2 __attribute__((ext_vector_type(2)));

__device__ __forceinline__ v2 vfma(v2 a, v2 b, v2 c) {
    return __builtin_elementwise_fma(a, b, c);
}
__device__ __forceinline__ v2 vmax0(v2 a) {
    return __builtin_elementwise_max(a, (v2)(0.f));
}

// lane l <- v[l-1] (whole wave), lane 0 <- v[48]
__device__ __forceinline__ float shift_up(float v, bool is0) {
    int iv  = __float_as_int(v);
    int s48 = __builtin_amdgcn_readlane(iv, 48);
    int sh  = __builtin_amdgcn_update_dpp(iv, iv, 0x138, 0xF, 0xF, false); // wave_shr:1
    sh = is0 ? s48 : sh;
    return __int_as_float(sh);
}

// lane l <- v[l+1] (whole wave), lane 48 <- v[0]
__device__ __forceinline__ float shift_dn(float v, bool is48) {
    int iv = __float_as_int(v);
    int s0 = __builtin_amdgcn_readlane(iv, 0);
    int sh = __builtin_amdgcn_update_dpp(iv, iv, 0x130, 0xF, 0xF, false); // wave_shl:1
    sh = is48 ? s0 : sh;
    return __int_as_float(sh);
}

__global__ __launch_bounds__(64) void pdhg_kernel(
    const float* __restrict__ price,
    const float* __restrict__ loadv,
    const float* __restrict__ pvv,
    const float* __restrict__ s0,
    float* __restrict__ out,
    int B,
    float tau)
{
    const int b = blockIdx.x;
    const int t = threadIdx.x;
    const bool lt  = (t < TT);
    const bool i48 = (t == 48);
    const bool i0  = (t == 0);

    const float A  = 0.999f;
    const float Bi = 0.95f;    // B00
    const float Bo = -1.05f;   // B01
    const float ts = tau * tau;     // tau*sigma (sigma == tau)

    float pr_ = 0.f, ld = 0.f, pv_ = 0.f;
    if (lt) {
        pr_ = price[(size_t)b*TT + t];
        ld  = loadv[(size_t)b*TT + t];
        pv_ = pvv  [(size_t)b*TT + t];
    }
    const float qe   = i48 ? s0[b] : 0.f;   // b_eq: zeros(T) then s0
    const float tsqe = ts * qe;

    // hoisted per-lane constant vectors
    const v2 tsv   = (v2)(ts);
    const v2 ntsv  = (v2)(-ts);
    const v2 BiBov = { -Bi, -Bo };
    const v2 tpv   = { tau * pr_, -tau * pr_ };    // tau*c for (in,out) and (pl,pr)
    const float tep = tau * 1.0e4f;                // tau*c_eps
    const v2 C12   = { 0.f,        ts * 13.5f };
    const v2 C35   = { ts * 5.f,   ts * 5.f   };
    const v2 C79   = { ts * (-ld), ts * (-pv_) };
    const v2 C810  = { ts * ld,    ts * pv_   };
    const v2 C1112 = { ts * 10.f,  ts * 10.f  };

    // primal state: xs scalar; pairs (in,out), (pl,pr); ep scalar
    float xs = 0.f, xep = 0.f;
    v2 xIO = (v2)(0.f), xPP = (v2)(0.f);
    // dual state (scaled by tau): ye scalar; rows paired
    float ye = 0.f;
    v2 G12 = (v2)(0.f), G35 = (v2)(0.f), G46 = (v2)(0.f),
       G79 = (v2)(0.f), G810 = (v2)(0.f), G1112 = (v2)(0.f);

    #pragma unroll 2
    for (int it = 0; it < N_ITERS; ++it) {
        // up-shift of ye: pure VALU (DPP + readlane + cndmask)
        const float yprev = shift_up(ye, i0);

        // ---- K^T y on scaled duals (= tau * K^T y) ----
        const v2 dv    = G1112 - G1112.yx;          // {d1112, -d1112}
        const v2 ktIO  = vfma((v2)(ye), BiBov, (G35 - G46) + dv);
        const v2 ktPP  = (G810 - G79) + dv;
        const v2 S     = G79 + G810;
        const float wep = tep - (S.x + S.y);        // tau*(c_ep + ktep)

        // ---- x' = x - (tau*c + tau*K^T y);  z = 2x' - x = x' - w ----
        const v2 wIO = ktIO + tpv;
        const v2 wPP = ktPP + tpv;
        const v2 xnIO = xIO - wIO;  const v2 zIO = xnIO - wIO;
        const v2 xnPP = xPP - wPP;  const v2 zPP = xnPP - wPP;
        const float xnep = xep - wep;  const float zep = xnep - wep;

        // s-path (consumes yprev)
        float kts = (yprev + (G12.y - G12.x)) - A * ye;
        kts = lt ? kts : yprev;
        const float xns = xs - kts;
        const float zs  = xns - kts;

        // down-shift of zs: pure VALU
        const float zsn = shift_dn(zs, i48);

        // ---- dual rows: G' = max(G + ts*e - ts*h, 0), e = rows of K z ----
        const v2 zsv  = { -zs, zs };
        const v2 zepv = (v2)(zep);
        const v2 sv   = zPP + zepv;                 // (zpl+zep, zpr+zep)
        const v2 dvv  = zPP - zepv;                 // (zpl-zep, zpr-zep)
        const v2 m11v = (zIO - zIO.yx) + (zPP - zPP.yx);  // {m11, -m11}

        G12   = vmax0(vfma(zsv,  tsv,  G12)  - C12);
        G35   = vmax0(vfma(zIO,  tsv,  G35)  - C35);
        G46   = vmax0(vfma(zIO,  ntsv, G46));           // h = 0
        G79   = vmax0(vfma(sv,   ntsv, G79)  - C79);
        G810  = vmax0(vfma(dvv,  tsv,  G810) - C810);
        G1112 = vmax0(vfma(m11v, tsv,  G1112) - C1112);

        // ---- equality dual (consumes zsn) ----
        float kze = fmaf(-A, zs, zsn);
        kze = fmaf(-Bi, zIO.x, kze);
        kze = fmaf(-Bo, zIO.y, kze);
        kze = lt ? kze : zsn;                       // lane 48: z_s[0]
        ye  = fmaf(ts, kze, ye) - tsqe;

        xs = xns; xIO = xnIO; xPP = xnPP; xep = xnep;
    }

    if (lt) {
        const size_t BT   = (size_t)B * TT;
        const size_t base = (size_t)b * TT + t;
        out[0*BT + base] = xIO.x;  // Ps_in
        out[1*BT + base] = xIO.y;  // Ps_out
        out[2*BT + base] = xPP.x;  // Pl
        out[3*BT + base] = xPP.y;  // Pr
        out[4*BT + base] = xep;    // eps
    }
}

// ---------------------------------------------------------------------------
// Host: ||K||_2 via matrix-free Lanczos (m=56, no reorth) on M = K^T K
// (289-dim closed form), lambda_max(T_m) via Sturm bisection. Deterministic.
// ---------------------------------------------------------------------------
static float compute_tau_host()
{
    const double A = 0.999, Bi = 0.95, Bo = -1.05;
    const int n = 289;            // 49 + 5*48
    const int OS = 0, OI = 49, OO = 97, OPL = 145, OPR = 193, OE = 241;

    double q[289], qp[289], w[289];

    auto applyM = [&](const double* v, double* u) {
        double we[TT + 1];
        for (int t = 0; t < TT; ++t)
            we[t] = v[OS + t + 1] - A * v[OS + t] - Bi * v[OI + t] - Bo * v[OO + t];
        we[TT] = v[OS + 0];
        for (int j = 0; j <= TT; ++j) {
            double r = (j >= 1) ? we[j - 1] : we[TT];
            if (j <= TT - 1) r += -A * we[j] + 2.0 * v[OS + j];
            u[OS + j] = r;
        }
        for (int t = 0; t < TT; ++t) {
            const double w11 = v[OI + t] - v[OO + t] + v[OPL + t] - v[OPR + t];
            u[OI  + t] = -Bi * we[t] + 2.0 * v[OI  + t] + 2.0 * w11;
            u[OO  + t] = -Bo * we[t] + 2.0 * v[OO  + t] - 2.0 * w11;
            u[OPL + t] =  2.0 * v[OPL + t] + 2.0 * w11;
            u[OPR + t] =  2.0 * v[OPR + t] - 2.0 * w11;
            u[OE  + t] =  4.0 * v[OE  + t];
        }
    };

    // deterministic init, normalized
    unsigned long long lcg = 0x243F6A8885A308D3ull;
    for (int i = 0; i < n; ++i) {
        lcg = lcg * 6364136223846793005ull + 1442695040888963407ull;
        q[i] = ((double)(lcg >> 11) / 9007199254740992.0) - 0.5;
    }
    {
        double s = 0; for (int i = 0; i < n; ++i) s += q[i]*q[i];
        const double inv = 1.0 / sqrt(s);
        for (int i = 0; i < n; ++i) q[i] *= inv;
    }

    const int MMAX = 56;
    double alpha[MMAX], beta[MMAX];
    for (int i = 0; i < n; ++i) qp[i] = 0.0;
    double bprev = 0.0;
    int m = MMAX;
    for (int j = 0; j < MMAX; ++j) {
        applyM(q, w);
        if (j > 0) for (int i = 0; i < n; ++i) w[i] -= bprev * qp[i];
        double a = 0; for (int i = 0; i < n; ++i) a += w[i] * q[i];
        alpha[j] = a;
        for (int i = 0; i < n; ++i) w[i] -= a * q[i];
        double s = 0; for (int i = 0; i < n; ++i) s += w[i]*w[i];
        const double bnx = sqrt(s);
        if (bnx < 1e-12) { m = j + 1; break; }
        beta[j] = bnx;
        const double inv = 1.0 / bnx;
        for (int i = 0; i < n; ++i) { qp[i] = q[i]; q[i] = w[i] * inv; }
        bprev = bnx;
    }

    double hi = 0.0;
    for (int i = 0; i < m; ++i) {
        double g = alpha[i] + (i > 0 ? fabs(beta[i-1]) : 0.0)
                            + (i < m-1 ? fabs(beta[i]) : 0.0);
        if (g > hi) hi = g;
    }
    hi += 1e-9; double lo = 0.0;
    for (int it = 0; it < 64; ++it) {
        const double mid = 0.5 * (lo + hi);
        int cnt = 0; double d = 1.0;
        for (int i = 0; i < m; ++i) {
            double tt = alpha[i] - mid - (i > 0 ? beta[i-1]*beta[i-1] / d : 0.0);
            if (tt < 0) ++cnt;
            if (fabs(tt) < 1e-30) tt = -1e-30;
            d = tt;
        }
        if (cnt >= m) hi = mid; else lo = mid;
    }
    double lam = 0.5 * (lo + hi);

    applyM(q, w);
    double rq = 0, nq = 0;
    for (int i = 0; i < n; ++i) { rq += q[i]*w[i]; nq += q[i]*q[i]; }
    rq /= nq;
    if (rq > lam) lam = rq;

    return (float)(0.95 / sqrt(lam));
}

extern "C" void kernel_launch(void* const* d_in, const int* in_sizes, int n_in,
                              void* d_out, int out_size, void* d_ws, size_t ws_size,
                              hipStream_t stream)
{
    const float* price = (const float*)d_in[0];
    const float* loadv = (const float*)d_in[1];
    const float* pvv   = (const float*)d_in[2];
    const float* s0    = (const float*)d_in[3];
    float* out = (float*)d_out;

    const int B = in_sizes[0] / TT;   // price_hat is (B, T)
    const float tau = compute_tau_host();

    pdhg_kernel<<<B, 64, 0, stream>>>(price, loadv, pvv, s0, out, B, tau);
}

// Round 6
// 43.791 us; speedup vs baseline: 49.6443x; 1.0036x over previous
//
#include <hip/hip_runtime.h>
#include <math.h>

// ---------------------------------------------------------------------------
// Batched PDHG (Chambolle-Pock), one wave per sample, lane t owns time step t.
// Round-6 structure (delta vs round 5):
//  - "u-package" restructuring: u = ye - ts*qe + ts*(own-lane part of K z row)
//    computed right after z; then ye_new = u + ts*zs[l+1] and next-iter
//    yprev = shift_up(u) + ts*zs[own]. Both cross-lane shifts (zs down, u up)
//    issue together with no mutual dependency -> serial cycle contains ONE
//    shift instead of two.
//  - scalar s-path and eps-path packed as one v2 {xs, xep}
//  - VOP3P .xx/.yy broadcasts replace explicit pair constructions
// ---------------------------------------------------------------------------

#define TT 48
#define N_ITERS 300

typedef float v2 __attribute__((ext_vector_type(2)));

__device__ __forceinline__ v2 vfma(v2 a, v2 b, v2 c) {
    return __builtin_elementwise_fma(a, b, c);
}
__device__ __forceinline__ v2 vmax0(v2 a) {
    return __builtin_elementwise_max(a, (v2)(0.f));
}

// lane l <- v[l-1] (whole wave), lane 0 <- v[48]
__device__ __forceinline__ float shift_up(float v, bool is0) {
    int iv  = __float_as_int(v);
    int s48 = __builtin_amdgcn_readlane(iv, 48);
    int sh  = __builtin_amdgcn_update_dpp(iv, iv, 0x138, 0xF, 0xF, false); // wave_shr:1
    sh = is0 ? s48 : sh;
    return __int_as_float(sh);
}

// lane l <- v[l+1] (whole wave), lane 48 <- v[0]
__device__ __forceinline__ float shift_dn(float v, bool is48) {
    int iv = __float_as_int(v);
    int s0 = __builtin_amdgcn_readlane(iv, 0);
    int sh = __builtin_amdgcn_update_dpp(iv, iv, 0x130, 0xF, 0xF, false); // wave_shl:1
    sh = is48 ? s0 : sh;
    return __int_as_float(sh);
}

__global__ __launch_bounds__(64) void pdhg_kernel(
    const float* __restrict__ price,
    const float* __restrict__ loadv,
    const float* __restrict__ pvv,
    const float* __restrict__ s0,
    float* __restrict__ out,
    int B,
    float tau)
{
    const int b = blockIdx.x;
    const int t = threadIdx.x;
    const bool lt  = (t < TT);
    const bool i48 = (t == 48);
    const bool i0  = (t == 0);

    const float A  = 0.999f;
    const float Bi = 0.95f;    // B00
    const float Bo = -1.05f;   // B01
    const float ts = tau * tau;     // tau*sigma (sigma == tau)

    float pr_ = 0.f, ld = 0.f, pv_ = 0.f;
    if (lt) {
        pr_ = price[(size_t)b*TT + t];
        ld  = loadv[(size_t)b*TT + t];
        pv_ = pvv  [(size_t)b*TT + t];
    }
    const float qe   = i48 ? s0[b] : 0.f;   // b_eq: zeros(T) then s0
    const float tsqe = ts * qe;

    // hoisted per-lane constants
    const v2 tsv   = (v2)(ts);
    const v2 ntsv  = (v2)(-ts);
    const v2 npts  = { -ts, ts };                  // for G12 (rows -zs, +zs)
    const v2 BiBov = { -Bi, -Bo };
    const float tsA  = ts * A;
    const float tsBi = ts * Bi;
    const float tsBo = ts * Bo;
    const v2 tpv   = { tau * pr_, -tau * pr_ };    // tau*c for (in,out)/(pl,pr)
    const float tep = tau * 1.0e4f;                // tau*c_eps
    const v2 C12   = { 0.f,        ts * 13.5f };
    const v2 C35   = { ts * 5.f,   ts * 5.f   };
    const v2 C79   = { ts * (-ld), ts * (-pv_) };
    const v2 C810  = { ts * ld,    ts * pv_   };
    const v2 C1112 = { ts * 10.f,  ts * 10.f  };

    // primal state: pairs (in,out), (pl,pr), (s,eps)
    v2 xIO = (v2)(0.f), xPP = (v2)(0.f), xSE = (v2)(0.f);
    // dual state (scaled by tau): ye scalar (+ yprev = shifted ye); rows paired
    float ye = 0.f, yprev = 0.f;
    v2 G12 = (v2)(0.f), G35 = (v2)(0.f), G46 = (v2)(0.f),
       G79 = (v2)(0.f), G810 = (v2)(0.f), G1112 = (v2)(0.f);

    #pragma unroll 2
    for (int it = 0; it < N_ITERS; ++it) {
        // ---- K^T y on scaled duals (= tau * K^T y) ----
        const v2 dv    = G1112 - G1112.yx;          // {d1112, -d1112}
        const v2 ktIO  = vfma((v2)(ye), BiBov, (G35 - G46) + dv);
        const v2 ktPP  = (G810 - G79) + dv;
        const v2 S     = G79 + G810;
        const float wep = tep - (S.x + S.y);        // tau*(c_ep + ktep)
        float kts = fmaf(-A, ye, yprev + (G12.y - G12.x));
        kts = lt ? kts : yprev;

        // ---- x' = x - w;  z = x' - w ----
        const v2 wIO = ktIO + tpv;
        const v2 wPP = ktPP + tpv;
        const v2 wSE = { kts, wep };
        const v2 xnIO = xIO - wIO;  const v2 zIO = xnIO - wIO;
        const v2 xnPP = xPP - wPP;  const v2 zPP = xnPP - wPP;
        const v2 xnSE = xSE - wSE;  const v2 zSE = xnSE - wSE;
        const float zs = zSE.x;

        // ---- u package: ye - ts*qe + ts*(own-lane part of K z eq-row) ----
        const float u0f = ye - tsqe;
        float uc = fmaf(-tsA,  zs,     u0f);
        uc       = fmaf(-tsBi, zIO.x,  uc);
        uc       = fmaf(-tsBo, zIO.y,  uc);
        const float u = lt ? uc : u0f;

        // ---- both shifts co-issued (no dependency between them) ----
        const float zsn = shift_dn(zs, i48);        // lane48 <- zs[0]
        const float us  = shift_up(u,  i0);         // lane0  <- u[48]

        // ---- dual rows: G' = max(G + ts*e - ts*h, 0) ----
        const v2 m11v = (zIO - zIO.yx) + (zPP - zPP.yx);  // {m11, -m11}
        G12   = vmax0(vfma(zSE.xx, npts, G12)  - C12);
        G35   = vmax0(vfma(zIO,    tsv,  G35)  - C35);
        G46   = vmax0(vfma(zIO,    ntsv, G46));
        G79   = vmax0(vfma(zSE.yy, ntsv, vfma(zPP, ntsv, G79))  - C79);
        G810  = vmax0(vfma(zSE.yy, ntsv, vfma(zPP, tsv,  G810)) - C810);
        G1112 = vmax0(vfma(m11v,   tsv,  G1112) - C1112);

        // ---- equality dual + pre-shifted ye for next iteration ----
        ye    = fmaf(ts, zsn, u);                   // ye_{i+1}[l]
        yprev = fmaf(ts, zs,  us);                  // ye_{i+1}[l-1] (wrap at 0)

        xSE = xnSE; xIO = xnIO; xPP = xnPP;
    }

    if (lt) {
        const size_t BT   = (size_t)B * TT;
        const size_t base = (size_t)b * TT + t;
        out[0*BT + base] = xIO.x;  // Ps_in
        out[1*BT + base] = xIO.y;  // Ps_out
        out[2*BT + base] = xPP.x;  // Pl
        out[3*BT + base] = xPP.y;  // Pr
        out[4*BT + base] = xSE.y;  // eps
    }
}

// ---------------------------------------------------------------------------
// Host: ||K||_2 via matrix-free Lanczos (m=56, no reorth) on M = K^T K
// (289-dim closed form), lambda_max(T_m) via Sturm bisection. Deterministic.
// ---------------------------------------------------------------------------
static float compute_tau_host()
{
    const double A = 0.999, Bi = 0.95, Bo = -1.05;
    const int n = 289;            // 49 + 5*48
    const int OS = 0, OI = 49, OO = 97, OPL = 145, OPR = 193, OE = 241;

    double q[289], qp[289], w[289];

    auto applyM = [&](const double* v, double* u) {
        double we[TT + 1];
        for (int t = 0; t < TT; ++t)
            we[t] = v[OS + t + 1] - A * v[OS + t] - Bi * v[OI + t] - Bo * v[OO + t];
        we[TT] = v[OS + 0];
        for (int j = 0; j <= TT; ++j) {
            double r = (j >= 1) ? we[j - 1] : we[TT];
            if (j <= TT - 1) r += -A * we[j] + 2.0 * v[OS + j];
            u[OS + j] = r;
        }
        for (int t = 0; t < TT; ++t) {
            const double w11 = v[OI + t] - v[OO + t] + v[OPL + t] - v[OPR + t];
            u[OI  + t] = -Bi * we[t] + 2.0 * v[OI  + t] + 2.0 * w11;
            u[OO  + t] = -Bo * we[t] + 2.0 * v[OO  + t] - 2.0 * w11;
            u[OPL + t] =  2.0 * v[OPL + t] + 2.0 * w11;
            u[OPR + t] =  2.0 * v[OPR + t] - 2.0 * w11;
            u[OE  + t] =  4.0 * v[OE  + t];
        }
    };

    // deterministic init, normalized
    unsigned long long lcg = 0x243F6A8885A308D3ull;
    for (int i = 0; i < n; ++i) {
        lcg = lcg * 6364136223846793005ull + 1442695040888963407ull;
        q[i] = ((double)(lcg >> 11) / 9007199254740992.0) - 0.5;
    }
    {
        double s = 0; for (int i = 0; i < n; ++i) s += q[i]*q[i];
        const double inv = 1.0 / sqrt(s);
        for (int i = 0; i < n; ++i) q[i] *= inv;
    }

    const int MMAX = 56;
    double alpha[MMAX], beta[MMAX];
    for (int i = 0; i < n; ++i) qp[i] = 0.0;
    double bprev = 0.0;
    int m = MMAX;
    for (int j = 0; j < MMAX; ++j) {
        applyM(q, w);
        if (j > 0) for (int i = 0; i < n; ++i) w[i] -= bprev * qp[i];
        double a = 0; for (int i = 0; i < n; ++i) a += w[i] * q[i];
        alpha[j] = a;
        for (int i = 0; i < n; ++i) w[i] -= a * q[i];
        double s = 0; for (int i = 0; i < n; ++i) s += w[i]*w[i];
        const double bnx = sqrt(s);
        if (bnx < 1e-12) { m = j + 1; break; }
        beta[j] = bnx;
        const double inv = 1.0 / bnx;
        for (int i = 0; i < n; ++i) { qp[i] = q[i]; q[i] = w[i] * inv; }
        bprev = bnx;
    }

    double hi = 0.0;
    for (int i = 0; i < m; ++i) {
        double g = alpha[i] + (i > 0 ? fabs(beta[i-1]) : 0.0)
                            + (i < m-1 ? fabs(beta[i]) : 0.0);
        if (g > hi) hi = g;
    }
    hi += 1e-9; double lo = 0.0;
    for (int it = 0; it < 64; ++it) {
        const double mid = 0.5 * (lo + hi);
        int cnt = 0; double d = 1.0;
        for (int i = 0; i < m; ++i) {
            double tt = alpha[i] - mid - (i > 0 ? beta[i-1]*beta[i-1] / d : 0.0);
            if (tt < 0) ++cnt;
            if (fabs(tt) < 1e-30) tt = -1e-30;
            d = tt;
        }
        if (cnt >= m) hi = mid; else lo = mid;
    }
    double lam = 0.5 * (lo + hi);

    applyM(q, w);
    double rq = 0, nq = 0;
    for (int i = 0; i < n; ++i) { rq += q[i]*w[i]; nq += q[i]*q[i]; }
    rq /= nq;
    if (rq > lam) lam = rq;

    return (float)(0.95 / sqrt(lam));
}

extern "C" void kernel_launch(void* const* d_in, const int* in_sizes, int n_in,
                              void* d_out, int out_size, void* d_ws, size_t ws_size,
                              hipStream_t stream)
{
    const float* price = (const float*)d_in[0];
    const float* loadv = (const float*)d_in[1];
    const float* pvv   = (const float*)d_in[2];
    const float* s0    = (const float*)d_in[3];
    float* out = (float*)d_out;

    const int B = in_sizes[0] / TT;   // price_hat is (B, T)
    const float tau = compute_tau_host();

    pdhg_kernel<<<B, 64, 0, stream>>>(price, loadv, pvv, s0, out, B, tau);
}